// Round 8
// baseline (417.229 us; speedup 1.0000x reference)
//
#include <hip/hip_runtime.h>

// MLP_48687749268221: out[e] = W3 @ relu(W2 @ relu(W1 @ concat(drug[i0],dis[i1]) + b1) + b2) + b3
// E = 2e6, dims 256 -> 128 -> 64 -> 1. bf16 MFMA, f32 accumulate.
// Round 8: tile loop with REGISTER-RESIDENT W1 (16 frags/wave, loaded once -> zero W1
// restream) + gather prefetch for tile t+1 issued before L1(t) (latency hidden under MFMA),
// A and H1 in separate LDS regions (49 KB -> 3 blocks/CU), 3 barriers/tile.

typedef __bf16 bf16x8 __attribute__((ext_vector_type(8)));
typedef unsigned short u16x8 __attribute__((ext_vector_type(8)));
typedef float f32x4 __attribute__((ext_vector_type(4)));

static __device__ __forceinline__ unsigned short f2b(float f) {
  // f32 -> bf16 RTNE (inputs finite)
  unsigned int u = __builtin_bit_cast(unsigned int, f);
  u += 0x7FFFu + ((u >> 16) & 1u);
  return (unsigned short)(u >> 16);
}

static __device__ __forceinline__ f32x4 mfma_bf16(u16x8 a, u16x8 b, f32x4 c) {
  return __builtin_amdgcn_mfma_f32_16x16x32_bf16(
      __builtin_bit_cast(bf16x8, a), __builtin_bit_cast(bf16x8, b), c, 0, 0, 0);
}

// ---------- prologue 1: f32 tables -> bf16 tables ----------
__global__ void cvt_tables(const float* __restrict__ a, const float* __restrict__ b,
                           unsigned short* __restrict__ oa, unsigned short* __restrict__ ob,
                           int na, int nb) {
  const int t = blockIdx.x * blockDim.x + threadIdx.x;
  const int ta = na >> 3;
  const float* src;
  unsigned short* dst;
  int i;
  if (t < ta) {
    src = a; dst = oa; i = t;
  } else {
    i = t - ta;
    if (i >= (nb >> 3)) return;
    src = b; dst = ob;
  }
  const float4 f0 = *(const float4*)(src + i * 8);
  const float4 f1 = *(const float4*)(src + i * 8 + 4);
  u16x8 v;
  v[0] = f2b(f0.x); v[1] = f2b(f0.y); v[2] = f2b(f0.z); v[3] = f2b(f0.w);
  v[4] = f2b(f1.x); v[5] = f2b(f1.y); v[6] = f2b(f1.z); v[7] = f2b(f1.w);
  *(u16x8*)(dst + i * 8) = v;
}

// ---------- prologue 2: weights -> bf16 in A-fragment order ----------
// Frag (16x16x32): lane l holds elem[dim][k], dim = 16*t + (l&15), k = 32*kt + 8*(l>>4) + j.
// W1 slot t = (ut*8 + kt)*64 + l  (ut 0..7, kt 0..7); W2: (nt2*4 + kt)*64 + l (nt2 0..3, kt 0..3).
__global__ void cvt_weights(const float* __restrict__ W1, const float* __restrict__ W2,
                            unsigned short* __restrict__ o1, unsigned short* __restrict__ o2) {
  const int t = blockIdx.x * blockDim.x + threadIdx.x;
  if (t < 4096) {
    const int l = t & 63, kt = (t >> 6) & 7, ut = t >> 9;
    const int n = 16 * ut + (l & 15), k0 = 32 * kt + 8 * (l >> 4);
    const float* src = W1 + n * 256 + k0;
    u16x8 v;
#pragma unroll
    for (int j = 0; j < 8; ++j) v[j] = f2b(src[j]);
    *(u16x8*)(o1 + t * 8) = v;
  } else if (t < 5120) {
    const int u = t - 4096;
    const int l = u & 63, kt = (u >> 6) & 3, nt = u >> 8;
    const int n = 16 * nt + (l & 15), k0 = 32 * kt + 8 * (l >> 4);
    const float* src = W2 + n * 128 + k0;
    u16x8 v;
#pragma unroll
    for (int j = 0; j < 8; ++j) v[j] = f2b(src[j]);
    *(u16x8*)(o2 + u * 8) = v;
  }
}

// ---------- main fused kernel ----------
// 256 threads = 4 waves; wave wn owns W1 units [32wn,+32), W2 units [16wn,+16), sweeps
// all 64 edges of each tile. LDS: A [64][512 B] swizzled @0 (32 KB); H1 [64][256 B]
// swizzled @32768 (16 KB); partials [4][64] f32 @49152. 50176 B -> 3 blocks/CU.
__global__ __launch_bounds__(256, 3) void mlp_fused(
    const unsigned short* __restrict__ drugB, const unsigned short* __restrict__ disB,
    const int* __restrict__ eidx, const unsigned short* __restrict__ w1frag,
    const unsigned short* __restrict__ w2frag, const float* __restrict__ b1,
    const float* __restrict__ b2, const float* __restrict__ W3,
    const float* __restrict__ b3, float* __restrict__ out, int E) {
  __shared__ __align__(16) unsigned char smem[32768 + 16384 + 1024];
  unsigned char* Abase = smem;
  unsigned char* Hbase = smem + 32768;
  float* partials = (float*)(smem + 49152);

  const int tid = threadIdx.x;
  const int wn = tid >> 6;   // wave 0..3
  const int l = tid & 63;
  const int l15 = l & 15;
  const int lq = l >> 4;
  const int T = (E + 63) >> 6;          // 31250 (E is an exact multiple of 64)
  const int stride = (int)gridDim.x;

  // ---- loop-invariant: W1 band register-resident (16 frags = 64 VGPR) ----
  u16x8 w1r[2][8];
  {
    const unsigned short* w1p = w1frag + ((2 * wn) * 512 + l) * 8;
#pragma unroll
    for (int uti = 0; uti < 2; ++uti)
#pragma unroll
      for (int kt = 0; kt < 8; ++kt)
        w1r[uti][kt] = *(const u16x8*)(w1p + (uti * 512 + kt * 64) * 8);
  }
  const float4 b1v0 = *(const float4*)(b1 + 32 * wn + 4 * lq);
  const float4 b1v1 = *(const float4*)(b1 + 32 * wn + 16 + 4 * lq);
  const float4 b2v = *(const float4*)(b2 + 16 * wn + 4 * lq);
  const float4 w3v = *(const float4*)(W3 + 16 * wn + 4 * lq);
  const float b3v = b3[0];

  // gather constants: wave wn covers byte-quarter [128*wn,+128) of every row; 1 row/lane
  const int gq = wn;
  const int gbase = gq * 128;
  const int gswz = (l & 7) << 4;
  unsigned char* growp = Abase + l * 512;

  int t = blockIdx.x;
  if (t >= T) return;

  // ---- prologue: gather tile t directly into LDS ----
  {
    int e = t * 64 + l;
    if (e >= E) e = E - 1;
    const int idx = eidx[(gq >> 1) * E + e];
    const unsigned short* src = ((gq < 2) ? drugB : disB) + (long)idx * 128 + (gq & 1) * 64;
#pragma unroll
    for (int c = 0; c < 8; ++c) {
      const u16x8 v = *(const u16x8*)(src + c * 8);
      *(u16x8*)(growp + ((gbase + c * 16) ^ gswz)) = v;
    }
  }
  __syncthreads();

  while (t < T) {
    const int tn = t + stride;
    // ---- prefetch gather for tile tn into registers (latency hides under L1) ----
    u16x8 g[8];
    {
      const int tc = (tn < T) ? tn : t;
      int e = tc * 64 + l;
      if (e >= E) e = E - 1;
      const int idx = eidx[(gq >> 1) * E + e];
      const unsigned short* src = ((gq < 2) ? drugB : disB) + (long)idx * 128 + (gq & 1) * 64;
#pragma unroll
      for (int c = 0; c < 8; ++c) g[c] = *(const u16x8*)(src + c * 8);
    }

    // ---- layer 1: D1[unit][edge]; A = resident W1 frags, B = edge frags from LDS ----
    f32x4 acc1[2][4];
#pragma unroll
    for (int uti = 0; uti < 2; ++uti)
#pragma unroll
      for (int nt = 0; nt < 4; ++nt) acc1[uti][nt] = (f32x4){0.f, 0.f, 0.f, 0.f};
#pragma unroll
    for (int kt = 0; kt < 8; ++kt) {
#pragma unroll
      for (int nt = 0; nt < 4; ++nt) {
        const int e = 16 * nt + l15;
        const u16x8 b =
            *(const u16x8*)(Abase + e * 512 + ((64 * kt + 16 * lq) ^ ((e & 7) << 4)));
        acc1[0][nt] = mfma_bf16(w1r[0][kt], b, acc1[0][nt]);
        acc1[1][nt] = mfma_bf16(w1r[1][kt], b, acc1[1][nt]);
      }
    }
    // W2 frags for this tile (cheap L2-hit reload; latency hidden under H1 phase)
    u16x8 w2f[4];
#pragma unroll
    for (int kt = 0; kt < 4; ++kt)
      w2f[kt] = *(const u16x8*)(w2frag + ((wn * 4 + kt) * 64 + l) * 8);
    __syncthreads();  // all waves done reading A(t)

    // ---- write A(tn) from prefetched regs ----
#pragma unroll
    for (int c = 0; c < 8; ++c)
      *(u16x8*)(growp + ((gbase + c * 16) ^ gswz)) = g[c];

    // ---- H1 epilogue: bias+relu, ds_write_b64 of 4 consecutive units ----
#pragma unroll
    for (int uti = 0; uti < 2; ++uti) {
      const float4 bv = uti ? b1v1 : b1v0;
#pragma unroll
      for (int nt = 0; nt < 4; ++nt) {
        const int e = 16 * nt + l15;
        float h0 = acc1[uti][nt][0] + bv.x; h0 = h0 > 0.f ? h0 : 0.f;
        float h1 = acc1[uti][nt][1] + bv.y; h1 = h1 > 0.f ? h1 : 0.f;
        float h2 = acc1[uti][nt][2] + bv.z; h2 = h2 > 0.f ? h2 : 0.f;
        float h3 = acc1[uti][nt][3] + bv.w; h3 = h3 > 0.f ? h3 : 0.f;
        ushort4 hv;
        hv.x = f2b(h0); hv.y = f2b(h1); hv.z = f2b(h2); hv.w = f2b(h3);
        *(ushort4*)(Hbase + e * 256 + ((64 * wn + 32 * uti + 8 * lq) ^ ((e & 7) << 4))) = hv;
      }
    }
    __syncthreads();  // H1 ready (A(tn) ready too)

    // ---- layer 2: D2[n2][edge]; A = W2 frags, B = H1 frags from LDS ----
    f32x4 acc2[4];
#pragma unroll
    for (int nt = 0; nt < 4; ++nt) acc2[nt] = (f32x4){0.f, 0.f, 0.f, 0.f};
#pragma unroll
    for (int kt = 0; kt < 4; ++kt) {
#pragma unroll
      for (int nt = 0; nt < 4; ++nt) {
        const int e = 16 * nt + l15;
        const u16x8 b =
            *(const u16x8*)(Hbase + e * 256 + ((64 * kt + 16 * lq) ^ ((e & 7) << 4)));
        acc2[nt] = mfma_bf16(w2f[kt], b, acc2[nt]);
      }
    }

    // ---- layer 3: relu(.+b2) dot W3 (4 units/lane), reduce over lq with 2 shuffles ----
#pragma unroll
    for (int nt = 0; nt < 4; ++nt) {
      float h0 = acc2[nt][0] + b2v.x; h0 = h0 > 0.f ? h0 : 0.f;
      float h1 = acc2[nt][1] + b2v.y; h1 = h1 > 0.f ? h1 : 0.f;
      float h2 = acc2[nt][2] + b2v.z; h2 = h2 > 0.f ? h2 : 0.f;
      float h3 = acc2[nt][3] + b2v.w; h3 = h3 > 0.f ? h3 : 0.f;
      float s = h0 * w3v.x + h1 * w3v.y + h2 * w3v.z + h3 * w3v.w;
      s += __shfl_xor(s, 16, 64);
      s += __shfl_xor(s, 32, 64);
      if (l < 16) partials[wn * 64 + 16 * nt + l15] = s;
    }
    __syncthreads();  // partials ready; also separates H1 reads from next H1 write

    if (tid < 64) {
      const int e = t * 64 + tid;
      if (e < E) {
        out[e] = partials[tid] + partials[64 + tid] + partials[128 + tid] +
                 partials[192 + tid] + b3v;
      }
    }
    t = tn;
  }
}

extern "C" void kernel_launch(void* const* d_in, const int* in_sizes, int n_in,
                              void* d_out, int out_size, void* d_ws, size_t ws_size,
                              hipStream_t stream) {
  const float* drug = (const float*)d_in[0];
  const float* dis = (const float*)d_in[1];
  const int* eidx = (const int*)d_in[2];
  const float* W1 = (const float*)d_in[3];
  const float* b1 = (const float*)d_in[4];
  const float* W2 = (const float*)d_in[5];
  const float* b2 = (const float*)d_in[6];
  const float* W3 = (const float*)d_in[7];
  const float* b3 = (const float*)d_in[8];
  float* out = (float*)d_out;

  const int na = in_sizes[0];           // 10000*128
  const int nb = in_sizes[1];           // 5000*128
  const int E = in_sizes[2] / 2;        // 2e6

  unsigned short* ws = (unsigned short*)d_ws;
  unsigned short* drugB = ws;
  unsigned short* disB = ws + na;
  unsigned short* w1f = ws + na + nb;
  unsigned short* w2f = w1f + 128 * 256;
  // total ws use: (na+nb)*2 + 81920 bytes ~= 3.92 MB

  const int tct = (na + nb) >> 3;
  cvt_tables<<<(tct + 255) / 256, 256, 0, stream>>>(drug, dis, drugB, disB, na, nb);
  cvt_weights<<<20, 256, 0, stream>>>(W1, W2, w1f, w2f);

  // 1536 blocks: ~20 tiles each; divides evenly at 2 or 3 resident blocks/CU
  mlp_fused<<<1536, 256, 0, stream>>>(drugB, disB, eidx, w1f, w2f, b1, b2, W3, b3, out, E);
}

// Round 9
// 277.514 us; speedup vs baseline: 1.5035x; 1.5035x over previous
//
#include <hip/hip_runtime.h>

// MLP_48687749268221: out[e] = W3 @ relu(W2 @ relu(W1 @ concat(drug[i0],dis[i1]) + b1) + b2) + b3
// E = 2e6, dims 256 -> 128 -> 64 -> 1. bf16 MFMA, f32 accumulate.
// Round 9: round-6 gather/L1/H1 (best known) + EDGE-SPLIT layers 2+3: wave wn computes all
// 64 n2-units for its own 16 edges -> H1 LDS reads 64->16 KB, no partials phase, 3 barriers,
// direct 64 B-aligned out stores. (Round 8's W1-register-residency spilled to scratch:
// WRITE_SIZE 74 MB; reverted.)

typedef __bf16 bf16x8 __attribute__((ext_vector_type(8)));
typedef unsigned short u16x8 __attribute__((ext_vector_type(8)));
typedef float f32x4 __attribute__((ext_vector_type(4)));

static __device__ __forceinline__ unsigned short f2b(float f) {
  // f32 -> bf16 RTNE (inputs finite)
  unsigned int u = __builtin_bit_cast(unsigned int, f);
  u += 0x7FFFu + ((u >> 16) & 1u);
  return (unsigned short)(u >> 16);
}

static __device__ __forceinline__ f32x4 mfma_bf16(u16x8 a, u16x8 b, f32x4 c) {
  return __builtin_amdgcn_mfma_f32_16x16x32_bf16(
      __builtin_bit_cast(bf16x8, a), __builtin_bit_cast(bf16x8, b), c, 0, 0, 0);
}

// ---------- prologue 1: f32 tables -> bf16 tables ----------
__global__ void cvt_tables(const float* __restrict__ a, const float* __restrict__ b,
                           unsigned short* __restrict__ oa, unsigned short* __restrict__ ob,
                           int na, int nb) {
  const int t = blockIdx.x * blockDim.x + threadIdx.x;
  const int ta = na >> 3;
  const float* src;
  unsigned short* dst;
  int i;
  if (t < ta) {
    src = a; dst = oa; i = t;
  } else {
    i = t - ta;
    if (i >= (nb >> 3)) return;
    src = b; dst = ob;
  }
  const float4 f0 = *(const float4*)(src + i * 8);
  const float4 f1 = *(const float4*)(src + i * 8 + 4);
  u16x8 v;
  v[0] = f2b(f0.x); v[1] = f2b(f0.y); v[2] = f2b(f0.z); v[3] = f2b(f0.w);
  v[4] = f2b(f1.x); v[5] = f2b(f1.y); v[6] = f2b(f1.z); v[7] = f2b(f1.w);
  *(u16x8*)(dst + i * 8) = v;
}

// ---------- prologue 2: weights -> bf16 in A-fragment order ----------
// Frag (16x16x32): lane l holds elem[dim][k], dim = 16*t + (l&15), k = 32*kt + 8*(l>>4) + j.
// W1 slot t = (ut*8 + kt)*64 + l  (ut 0..7, kt 0..7); W2: (nt2*4 + kt)*64 + l (nt2 0..3, kt 0..3).
__global__ void cvt_weights(const float* __restrict__ W1, const float* __restrict__ W2,
                            unsigned short* __restrict__ o1, unsigned short* __restrict__ o2) {
  const int t = blockIdx.x * blockDim.x + threadIdx.x;
  if (t < 4096) {
    const int l = t & 63, kt = (t >> 6) & 7, ut = t >> 9;
    const int n = 16 * ut + (l & 15), k0 = 32 * kt + 8 * (l >> 4);
    const float* src = W1 + n * 256 + k0;
    u16x8 v;
#pragma unroll
    for (int j = 0; j < 8; ++j) v[j] = f2b(src[j]);
    *(u16x8*)(o1 + t * 8) = v;
  } else if (t < 5120) {
    const int u = t - 4096;
    const int l = u & 63, kt = (u >> 6) & 3, nt = u >> 8;
    const int n = 16 * nt + (l & 15), k0 = 32 * kt + 8 * (l >> 4);
    const float* src = W2 + n * 128 + k0;
    u16x8 v;
#pragma unroll
    for (int j = 0; j < 8; ++j) v[j] = f2b(src[j]);
    *(u16x8*)(o2 + u * 8) = v;
  }
}

// ---------- main fused kernel ----------
// 256 threads = 4 waves. L1: wave wn owns units [32wn,+32), all 64 edges (round-6 proven).
// L2+L3: wave wn owns edges [16wn,+16), ALL 64 n2-units -> H1 read has no duplication,
// out written directly (one 64 B store per wave). LDS: A [64][512 B] swizzled, H1 [64][256 B]
// aliased over A. ~33 KB -> 4 blocks/CU.
__global__ __launch_bounds__(256, 4) void mlp_fused(
    const unsigned short* __restrict__ drugB, const unsigned short* __restrict__ disB,
    const int* __restrict__ eidx, const unsigned short* __restrict__ w1frag,
    const unsigned short* __restrict__ w2frag, const float* __restrict__ b1,
    const float* __restrict__ b2, const float* __restrict__ W3,
    const float* __restrict__ b3, float* __restrict__ out, int E) {
  __shared__ __align__(16) unsigned char smem[32768];
  unsigned char* Abase = smem;

  const int tid = threadIdx.x;
  const int wn = tid >> 6;   // wave 0..3
  const int l = tid & 63;
  const int l15 = l & 15;
  const int lq = l >> 4;
  const int e0 = blockIdx.x * 64;

  // ---- gather: wave wn writes byte-quarter [128*wn, +128) of ALL 64 rows; 1 row/lane ----
  {
    const int q = wn;
    int e = e0 + l;
    if (e >= E) e = E - 1;
    const int idx = eidx[(q >> 1) * E + e];  // q<2: drug, q>=2: dis
    const unsigned short* src = ((q < 2) ? drugB : disB) + (long)idx * 128 + (q & 1) * 64;
    unsigned char* rowp = Abase + l * 512;
    const int base = q * 128;
    const int swz = (l & 7) << 4;
#pragma unroll
    for (int c = 0; c < 8; ++c) {
      const u16x8 v = *(const u16x8*)(src + c * 8);
      *(u16x8*)(rowp + ((base + c * 16) ^ swz)) = v;
    }
  }

  const float4 b1v0 = *(const float4*)(b1 + 32 * wn + 4 * lq);
  const float4 b1v1 = *(const float4*)(b1 + 32 * wn + 16 + 4 * lq);
  __syncthreads();

  // ---- layer 1: D1[unit][edge]; A = W1 frags (2-deep stream), B = edge frags from LDS ----
  f32x4 acc1[2][4];
#pragma unroll
  for (int uti = 0; uti < 2; ++uti)
#pragma unroll
    for (int nt = 0; nt < 4; ++nt) acc1[uti][nt] = (f32x4){0.f, 0.f, 0.f, 0.f};

  const unsigned short* w1p = w1frag + ((2 * wn) * 512 + l) * 8;
  u16x8 nf[2][2];  // [kt parity][uti]; kt+2 prefetch
  nf[0][0] = *(const u16x8*)(w1p);
  nf[0][1] = *(const u16x8*)(w1p + 512 * 8);
  nf[1][0] = *(const u16x8*)(w1p + 64 * 8);
  nf[1][1] = *(const u16x8*)(w1p + (512 + 64) * 8);
#pragma unroll
  for (int kt = 0; kt < 8; ++kt) {
    const u16x8 c0 = nf[kt & 1][0], c1 = nf[kt & 1][1];
    if (kt < 6) {
      nf[kt & 1][0] = *(const u16x8*)(w1p + ((kt + 2) * 64) * 8);
      nf[kt & 1][1] = *(const u16x8*)(w1p + ((512 + (kt + 2) * 64)) * 8);
    }
#pragma unroll
    for (int nt = 0; nt < 4; ++nt) {
      const int e = 16 * nt + l15;
      const u16x8 b = *(const u16x8*)(Abase + e * 512 + ((64 * kt + 16 * lq) ^ ((e & 7) << 4)));
      acc1[0][nt] = mfma_bf16(c0, b, acc1[0][nt]);
      acc1[1][nt] = mfma_bf16(c1, b, acc1[1][nt]);
    }
  }
  __syncthreads();  // all waves done reading A before H1 overwrites it

  // ---- H1 epilogue: bias+relu, pack 4 bf16 (consecutive units) -> ds_write_b64 ----
  // lane holds D1[32wn + 16uti + 4lq + i][16nt + l15]
#pragma unroll
  for (int uti = 0; uti < 2; ++uti) {
    const float4 bv = uti ? b1v1 : b1v0;
#pragma unroll
    for (int nt = 0; nt < 4; ++nt) {
      const int e = 16 * nt + l15;
      float h0 = acc1[uti][nt][0] + bv.x; h0 = h0 > 0.f ? h0 : 0.f;
      float h1 = acc1[uti][nt][1] + bv.y; h1 = h1 > 0.f ? h1 : 0.f;
      float h2 = acc1[uti][nt][2] + bv.z; h2 = h2 > 0.f ? h2 : 0.f;
      float h3 = acc1[uti][nt][3] + bv.w; h3 = h3 > 0.f ? h3 : 0.f;
      ushort4 hv;
      hv.x = f2b(h0); hv.y = f2b(h1); hv.z = f2b(h2); hv.w = f2b(h3);
      *(ushort4*)(Abase + e * 256 + ((64 * wn + 32 * uti + 8 * lq) ^ ((e & 7) << 4))) = hv;
    }
  }
  __syncthreads();

  // ---- layer 2 (edge-split): D2[n2][e], e = 16wn + l15 (wave's own 16 edges) ----
  // A = W2 frags (nt2 0..3, kt 0..3, streamed), B = H1 frags of wave's edges.
  const int e = 16 * wn + l15;
  f32x4 acc2[4];
#pragma unroll
  for (int nt = 0; nt < 4; ++nt) acc2[nt] = (f32x4){0.f, 0.f, 0.f, 0.f};
#pragma unroll
  for (int kt = 0; kt < 4; ++kt) {
    const u16x8 b = *(const u16x8*)(Abase + e * 256 + ((64 * kt + 16 * lq) ^ ((e & 7) << 4)));
#pragma unroll
    for (int nt = 0; nt < 4; ++nt) {
      const u16x8 a = *(const u16x8*)(w2frag + ((nt * 4 + kt) * 64 + l) * 8);
      acc2[nt] = mfma_bf16(a, b, acc2[nt]);
    }
  }

  // ---- layer 3: out[e] = sum_n2 relu(D2[n2][e]+b2[n2])*W3[n2] + b3 ----
  // lane holds D2[16nt + 4lq + i][e]; dot locally then reduce over lq (2 shuffles).
  float s = 0.f;
#pragma unroll
  for (int nt = 0; nt < 4; ++nt) {
    const float4 b2v = *(const float4*)(b2 + 16 * nt + 4 * lq);
    const float4 w3v = *(const float4*)(W3 + 16 * nt + 4 * lq);
    float h;
    h = acc2[nt][0] + b2v.x; s += (h > 0.f ? h : 0.f) * w3v.x;
    h = acc2[nt][1] + b2v.y; s += (h > 0.f ? h : 0.f) * w3v.y;
    h = acc2[nt][2] + b2v.z; s += (h > 0.f ? h : 0.f) * w3v.z;
    h = acc2[nt][3] + b2v.w; s += (h > 0.f ? h : 0.f) * w3v.w;
  }
  s += __shfl_xor(s, 16, 64);
  s += __shfl_xor(s, 32, 64);
  if (l < 16) {
    const int eo = e0 + 16 * wn + l15;
    if (eo < E) out[eo] = s + b3[0];
  }
}

extern "C" void kernel_launch(void* const* d_in, const int* in_sizes, int n_in,
                              void* d_out, int out_size, void* d_ws, size_t ws_size,
                              hipStream_t stream) {
  const float* drug = (const float*)d_in[0];
  const float* dis = (const float*)d_in[1];
  const int* eidx = (const int*)d_in[2];
  const float* W1 = (const float*)d_in[3];
  const float* b1 = (const float*)d_in[4];
  const float* W2 = (const float*)d_in[5];
  const float* b2 = (const float*)d_in[6];
  const float* W3 = (const float*)d_in[7];
  const float* b3 = (const float*)d_in[8];
  float* out = (float*)d_out;

  const int na = in_sizes[0];           // 10000*128
  const int nb = in_sizes[1];           // 5000*128
  const int E = in_sizes[2] / 2;        // 2e6

  unsigned short* ws = (unsigned short*)d_ws;
  unsigned short* drugB = ws;
  unsigned short* disB = ws + na;
  unsigned short* w1f = ws + na + nb;
  unsigned short* w2f = w1f + 128 * 256;
  // total ws use: (na+nb)*2 + 81920 bytes ~= 3.92 MB

  const int tct = (na + nb) >> 3;
  cvt_tables<<<(tct + 255) / 256, 256, 0, stream>>>(drug, dis, drugB, disB, na, nb);
  cvt_weights<<<20, 256, 0, stream>>>(W1, W2, w1f, w2f);

  const int grid = (E + 63) / 64;
  mlp_fused<<<grid, 256, 0, stream>>>(drugB, disB, eidx, w1f, w2f, b1, b2, W3, b3, out, E);
}

// Round 10
// 264.717 us; speedup vs baseline: 1.5761x; 1.0483x over previous
//
#include <hip/hip_runtime.h>

// MLP_48687749268221: out[e] = W3 @ relu(W2 @ relu(W1 @ concat(drug[i0],dis[i1]) + b1) + b2) + b3
// E = 2e6, dims 256 -> 128 -> 64 -> 1. bf16 MFMA, f32 accumulate.
// Round 10: round-6 (best: 227us) with partials ALIASED into the dead upper A-region ->
// smem exactly 32768 B -> 5 blocks/CU (was 4), 5 independent barrier groups.
// (Rounds 5/7/9 lesson: any structure whose loads the compiler can sink goes latency-bound;
// round-6's load schedule is the only proven-good one — keep it byte-identical.)

typedef __bf16 bf16x8 __attribute__((ext_vector_type(8)));
typedef unsigned short u16x8 __attribute__((ext_vector_type(8)));
typedef float f32x4 __attribute__((ext_vector_type(4)));

static __device__ __forceinline__ unsigned short f2b(float f) {
  // f32 -> bf16 RTNE (inputs finite)
  unsigned int u = __builtin_bit_cast(unsigned int, f);
  u += 0x7FFFu + ((u >> 16) & 1u);
  return (unsigned short)(u >> 16);
}

static __device__ __forceinline__ f32x4 mfma_bf16(u16x8 a, u16x8 b, f32x4 c) {
  return __builtin_amdgcn_mfma_f32_16x16x32_bf16(
      __builtin_bit_cast(bf16x8, a), __builtin_bit_cast(bf16x8, b), c, 0, 0, 0);
}

// ---------- prologue 1: f32 tables -> bf16 tables ----------
__global__ void cvt_tables(const float* __restrict__ a, const float* __restrict__ b,
                           unsigned short* __restrict__ oa, unsigned short* __restrict__ ob,
                           int na, int nb) {
  const int t = blockIdx.x * blockDim.x + threadIdx.x;
  const int ta = na >> 3;
  const float* src;
  unsigned short* dst;
  int i;
  if (t < ta) {
    src = a; dst = oa; i = t;
  } else {
    i = t - ta;
    if (i >= (nb >> 3)) return;
    src = b; dst = ob;
  }
  const float4 f0 = *(const float4*)(src + i * 8);
  const float4 f1 = *(const float4*)(src + i * 8 + 4);
  u16x8 v;
  v[0] = f2b(f0.x); v[1] = f2b(f0.y); v[2] = f2b(f0.z); v[3] = f2b(f0.w);
  v[4] = f2b(f1.x); v[5] = f2b(f1.y); v[6] = f2b(f1.z); v[7] = f2b(f1.w);
  *(u16x8*)(dst + i * 8) = v;
}

// ---------- prologue 2: weights -> bf16 in A-fragment order ----------
// Frag (16x16x32): lane l holds elem[dim][k], dim = 16*t + (l&15), k = 32*kt + 8*(l>>4) + j.
// W1 slot t = (ut*8 + kt)*64 + l  (ut 0..7, kt 0..7); W2: (nt2*4 + kt)*64 + l (nt2 0..3, kt 0..3).
__global__ void cvt_weights(const float* __restrict__ W1, const float* __restrict__ W2,
                            unsigned short* __restrict__ o1, unsigned short* __restrict__ o2) {
  const int t = blockIdx.x * blockDim.x + threadIdx.x;
  if (t < 4096) {
    const int l = t & 63, kt = (t >> 6) & 7, ut = t >> 9;
    const int n = 16 * ut + (l & 15), k0 = 32 * kt + 8 * (l >> 4);
    const float* src = W1 + n * 256 + k0;
    u16x8 v;
#pragma unroll
    for (int j = 0; j < 8; ++j) v[j] = f2b(src[j]);
    *(u16x8*)(o1 + t * 8) = v;
  } else if (t < 5120) {
    const int u = t - 4096;
    const int l = u & 63, kt = (u >> 6) & 3, nt = u >> 8;
    const int n = 16 * nt + (l & 15), k0 = 32 * kt + 8 * (l >> 4);
    const float* src = W2 + n * 128 + k0;
    u16x8 v;
#pragma unroll
    for (int j = 0; j < 8; ++j) v[j] = f2b(src[j]);
    *(u16x8*)(o2 + u * 8) = v;
  }
}

// ---------- main fused kernel ----------
// 256 threads = 4 waves; wave wn owns W1 units [32wn,+32) and W2 units [16wn,+16),
// sweeps all 64 edges. LDS (32768 B total -> 5 blocks/CU):
//   A [64][512 B] swizzled @0 (32 KB); H1 [64][256 B] aliased @0 after L1;
//   partials [4][64] f32 @16384 (dead upper-A region, disjoint from H1).
__global__ __launch_bounds__(256, 5) void mlp_fused(
    const unsigned short* __restrict__ drugB, const unsigned short* __restrict__ disB,
    const int* __restrict__ eidx, const unsigned short* __restrict__ w1frag,
    const unsigned short* __restrict__ w2frag, const float* __restrict__ b1,
    const float* __restrict__ b2, const float* __restrict__ W3,
    const float* __restrict__ b3, float* __restrict__ out, int E) {
  __shared__ __align__(16) unsigned char smem[32768];
  unsigned char* Abase = smem;
  float* partials = (float*)(smem + 16384);

  const int tid = threadIdx.x;
  const int wn = tid >> 6;   // wave 0..3: unit-column quarter (and gather byte-quarter)
  const int l = tid & 63;
  const int l15 = l & 15;
  const int lq = l >> 4;
  const int e0 = blockIdx.x * 64;

  // ---- gather: wave wn writes byte-quarter [128*wn, +128) of ALL 64 rows; 1 row/lane ----
  {
    const int q = wn;
    int e = e0 + l;
    if (e >= E) e = E - 1;
    const int idx = eidx[(q >> 1) * E + e];  // q<2: drug, q>=2: dis
    const unsigned short* src = ((q < 2) ? drugB : disB) + (long)idx * 128 + (q & 1) * 64;
    unsigned char* rowp = Abase + l * 512;
    const int base = q * 128;
    const int swz = (l & 7) << 4;
#pragma unroll
    for (int c = 0; c < 8; ++c) {
      const u16x8 v = *(const u16x8*)(src + c * 8);
      *(u16x8*)(rowp + ((base + c * 16) ^ swz)) = v;
    }
  }

  // ---- W2 A-frags resident (hidden under gather), bias/W3 float4 per lane ----
  u16x8 w2f[4];
#pragma unroll
  for (int kt = 0; kt < 4; ++kt)
    w2f[kt] = *(const u16x8*)(w2frag + ((wn * 4 + kt) * 64 + l) * 8);
  const float4 b1v0 = *(const float4*)(b1 + 32 * wn + 4 * lq);
  const float4 b1v1 = *(const float4*)(b1 + 32 * wn + 16 + 4 * lq);
  const float4 b2v = *(const float4*)(b2 + 16 * wn + 4 * lq);
  const float4 w3v = *(const float4*)(W3 + 16 * wn + 4 * lq);
  __syncthreads();

  // ---- layer 1: D1[unit][edge]; A = W1 frags (2-deep stream), B = edge frags from LDS ----
  f32x4 acc1[2][4];
#pragma unroll
  for (int uti = 0; uti < 2; ++uti)
#pragma unroll
    for (int nt = 0; nt < 4; ++nt) acc1[uti][nt] = (f32x4){0.f, 0.f, 0.f, 0.f};

  const unsigned short* w1p = w1frag + ((2 * wn) * 512 + l) * 8;
  u16x8 nf[2][2];  // [kt parity][uti]; kt+2 prefetch
  nf[0][0] = *(const u16x8*)(w1p);
  nf[0][1] = *(const u16x8*)(w1p + 512 * 8);
  nf[1][0] = *(const u16x8*)(w1p + 64 * 8);
  nf[1][1] = *(const u16x8*)(w1p + (512 + 64) * 8);
#pragma unroll
  for (int kt = 0; kt < 8; ++kt) {
    const u16x8 c0 = nf[kt & 1][0], c1 = nf[kt & 1][1];
    if (kt < 6) {
      nf[kt & 1][0] = *(const u16x8*)(w1p + ((kt + 2) * 64) * 8);
      nf[kt & 1][1] = *(const u16x8*)(w1p + ((512 + (kt + 2) * 64)) * 8);
    }
#pragma unroll
    for (int nt = 0; nt < 4; ++nt) {
      const int e = 16 * nt + l15;
      const u16x8 b = *(const u16x8*)(Abase + e * 512 + ((64 * kt + 16 * lq) ^ ((e & 7) << 4)));
      acc1[0][nt] = mfma_bf16(c0, b, acc1[0][nt]);
      acc1[1][nt] = mfma_bf16(c1, b, acc1[1][nt]);
    }
  }
  __syncthreads();  // all waves done reading A before H1 overwrites it

  // ---- H1 epilogue: bias+relu, pack 4 bf16 (consecutive units) -> ds_write_b64 ----
  // lane holds D1[32wn + 16uti + 4lq + i][16nt + l15]
#pragma unroll
  for (int uti = 0; uti < 2; ++uti) {
    const float4 bv = uti ? b1v1 : b1v0;
#pragma unroll
    for (int nt = 0; nt < 4; ++nt) {
      const int e = 16 * nt + l15;
      float h0 = acc1[uti][nt][0] + bv.x; h0 = h0 > 0.f ? h0 : 0.f;
      float h1 = acc1[uti][nt][1] + bv.y; h1 = h1 > 0.f ? h1 : 0.f;
      float h2 = acc1[uti][nt][2] + bv.z; h2 = h2 > 0.f ? h2 : 0.f;
      float h3 = acc1[uti][nt][3] + bv.w; h3 = h3 > 0.f ? h3 : 0.f;
      ushort4 hv;
      hv.x = f2b(h0); hv.y = f2b(h1); hv.z = f2b(h2); hv.w = f2b(h3);
      *(ushort4*)(Abase + e * 256 + ((64 * wn + 32 * uti + 8 * lq) ^ ((e & 7) << 4))) = hv;
    }
  }
  __syncthreads();

  // ---- layer 2: D2[n2][edge]; A = W2 frags (resident), B = H1 frags from LDS ----
  f32x4 acc2[4];
#pragma unroll
  for (int nt = 0; nt < 4; ++nt) acc2[nt] = (f32x4){0.f, 0.f, 0.f, 0.f};
#pragma unroll
  for (int kt = 0; kt < 4; ++kt) {
#pragma unroll
    for (int nt = 0; nt < 4; ++nt) {
      const int e = 16 * nt + l15;
      const u16x8 b = *(const u16x8*)(Abase + e * 256 + ((64 * kt + 16 * lq) ^ ((e & 7) << 4)));
      acc2[nt] = mfma_bf16(w2f[kt], b, acc2[nt]);
    }
  }

  // ---- layer 3: relu(.+b2) dot W3 (4 units per lane), reduce over lq with 2 shuffles ----
  // partials live at smem+16384 (disjoint from H1 [0,16384)) -> no cross-wave hazard.
#pragma unroll
  for (int nt = 0; nt < 4; ++nt) {
    float h0 = acc2[nt][0] + b2v.x; h0 = h0 > 0.f ? h0 : 0.f;
    float h1 = acc2[nt][1] + b2v.y; h1 = h1 > 0.f ? h1 : 0.f;
    float h2 = acc2[nt][2] + b2v.z; h2 = h2 > 0.f ? h2 : 0.f;
    float h3 = acc2[nt][3] + b2v.w; h3 = h3 > 0.f ? h3 : 0.f;
    float s = h0 * w3v.x + h1 * w3v.y + h2 * w3v.z + h3 * w3v.w;
    s += __shfl_xor(s, 16, 64);
    s += __shfl_xor(s, 32, 64);
    if (l < 16) partials[wn * 64 + 16 * nt + l15] = s;
  }
  __syncthreads();

  if (tid < 64) {
    const int e = e0 + tid;
    if (e < E) {
      out[e] = partials[tid] + partials[64 + tid] + partials[128 + tid] +
               partials[192 + tid] + b3[0];
    }
  }
}

extern "C" void kernel_launch(void* const* d_in, const int* in_sizes, int n_in,
                              void* d_out, int out_size, void* d_ws, size_t ws_size,
                              hipStream_t stream) {
  const float* drug = (const float*)d_in[0];
  const float* dis = (const float*)d_in[1];
  const int* eidx = (const int*)d_in[2];
  const float* W1 = (const float*)d_in[3];
  const float* b1 = (const float*)d_in[4];
  const float* W2 = (const float*)d_in[5];
  const float* b2 = (const float*)d_in[6];
  const float* W3 = (const float*)d_in[7];
  const float* b3 = (const float*)d_in[8];
  float* out = (float*)d_out;

  const int na = in_sizes[0];           // 10000*128
  const int nb = in_sizes[1];           // 5000*128
  const int E = in_sizes[2] / 2;        // 2e6

  unsigned short* ws = (unsigned short*)d_ws;
  unsigned short* drugB = ws;
  unsigned short* disB = ws + na;
  unsigned short* w1f = ws + na + nb;
  unsigned short* w2f = w1f + 128 * 256;
  // total ws use: (na+nb)*2 + 81920 bytes ~= 3.92 MB

  const int tct = (na + nb) >> 3;
  cvt_tables<<<(tct + 255) / 256, 256, 0, stream>>>(drug, dis, drugB, disB, na, nb);
  cvt_weights<<<20, 256, 0, stream>>>(W1, W2, w1f, w2f);

  const int grid = (E + 63) / 64;
  mlp_fused<<<grid, 256, 0, stream>>>(drugB, disB, eidx, w1f, w2f, b1, b2, W3, b3, out, E);
}

// Round 11
// 224.094 us; speedup vs baseline: 1.8618x; 1.1813x over previous
//
#include <hip/hip_runtime.h>

// MLP_48687749268221: out[e] = W3 @ relu(W2 @ relu(W1 @ concat(drug[i0],dis[i1]) + b1) + b2) + b3
// E = 2e6, dims 256 -> 128 -> 64 -> 1. bf16 MFMA, f32 accumulate.
// Round 11: round-6 schedule with a CHUNKED LINEAR LDS layout A[chunk][edge][16B]
// (chunk = kt*4+lq). Gather writes 1KB contiguous/instr, B-frag reads 256B contiguous
// per quarter-wave, H1 writes stride-16 -> ZERO structural bank conflicts, no XOR math.
// (512B-stride XOR layout was 8-way on gather writes: bank window is only 128B.)

typedef __bf16 bf16x8 __attribute__((ext_vector_type(8)));
typedef unsigned short u16x8 __attribute__((ext_vector_type(8)));
typedef float f32x4 __attribute__((ext_vector_type(4)));

static __device__ __forceinline__ unsigned short f2b(float f) {
  // f32 -> bf16 RTNE (inputs finite)
  unsigned int u = __builtin_bit_cast(unsigned int, f);
  u += 0x7FFFu + ((u >> 16) & 1u);
  return (unsigned short)(u >> 16);
}

static __device__ __forceinline__ f32x4 mfma_bf16(u16x8 a, u16x8 b, f32x4 c) {
  return __builtin_amdgcn_mfma_f32_16x16x32_bf16(
      __builtin_bit_cast(bf16x8, a), __builtin_bit_cast(bf16x8, b), c, 0, 0, 0);
}

// ---------- prologue 1: f32 tables -> bf16 tables ----------
__global__ void cvt_tables(const float* __restrict__ a, const float* __restrict__ b,
                           unsigned short* __restrict__ oa, unsigned short* __restrict__ ob,
                           int na, int nb) {
  const int t = blockIdx.x * blockDim.x + threadIdx.x;
  const int ta = na >> 3;
  const float* src;
  unsigned short* dst;
  int i;
  if (t < ta) {
    src = a; dst = oa; i = t;
  } else {
    i = t - ta;
    if (i >= (nb >> 3)) return;
    src = b; dst = ob;
  }
  const float4 f0 = *(const float4*)(src + i * 8);
  const float4 f1 = *(const float4*)(src + i * 8 + 4);
  u16x8 v;
  v[0] = f2b(f0.x); v[1] = f2b(f0.y); v[2] = f2b(f0.z); v[3] = f2b(f0.w);
  v[4] = f2b(f1.x); v[5] = f2b(f1.y); v[6] = f2b(f1.z); v[7] = f2b(f1.w);
  *(u16x8*)(dst + i * 8) = v;
}

// ---------- prologue 2: weights -> bf16 in A-fragment order ----------
// Frag (16x16x32): lane l holds elem[dim][k], dim = 16*t + (l&15), k = 32*kt + 8*(l>>4) + j.
// W1 slot t = (ut*8 + kt)*64 + l  (ut 0..7, kt 0..7); W2: (nt2*4 + kt)*64 + l (nt2 0..3, kt 0..3).
__global__ void cvt_weights(const float* __restrict__ W1, const float* __restrict__ W2,
                            unsigned short* __restrict__ o1, unsigned short* __restrict__ o2) {
  const int t = blockIdx.x * blockDim.x + threadIdx.x;
  if (t < 4096) {
    const int l = t & 63, kt = (t >> 6) & 7, ut = t >> 9;
    const int n = 16 * ut + (l & 15), k0 = 32 * kt + 8 * (l >> 4);
    const float* src = W1 + n * 256 + k0;
    u16x8 v;
#pragma unroll
    for (int j = 0; j < 8; ++j) v[j] = f2b(src[j]);
    *(u16x8*)(o1 + t * 8) = v;
  } else if (t < 5120) {
    const int u = t - 4096;
    const int l = u & 63, kt = (u >> 6) & 3, nt = u >> 8;
    const int n = 16 * nt + (l & 15), k0 = 32 * kt + 8 * (l >> 4);
    const float* src = W2 + n * 128 + k0;
    u16x8 v;
#pragma unroll
    for (int j = 0; j < 8; ++j) v[j] = f2b(src[j]);
    *(u16x8*)(o2 + u * 8) = v;
  }
}

// ---------- main fused kernel ----------
// 256 threads = 4 waves; wave wn owns W1 units [32wn,+32) and W2 units [16wn,+16),
// sweeps all 64 edges (round-6 schedule). LDS (33792 B -> 4 blocks/CU):
//   A: 32 chunks x [64 edges x 16 B] @0 (32 KB), chunk = kt*4+lq (feature f: kt=f>>5,
//      lq=(f>>3)&3, j=f&7).  H1: 16 chunks (kt2*4+lq) aliased @0 after L1 barrier (16 KB).
//   partials [4][64] f32 @32768.
__global__ __launch_bounds__(256, 4) void mlp_fused(
    const unsigned short* __restrict__ drugB, const unsigned short* __restrict__ disB,
    const int* __restrict__ eidx, const unsigned short* __restrict__ w1frag,
    const unsigned short* __restrict__ w2frag, const float* __restrict__ b1,
    const float* __restrict__ b2, const float* __restrict__ W3,
    const float* __restrict__ b3, float* __restrict__ out, int E) {
  __shared__ __align__(16) unsigned char smem[33792];
  unsigned char* Abase = smem;
  float* partials = (float*)(smem + 32768);

  const int tid = threadIdx.x;
  const int wn = tid >> 6;   // wave 0..3: unit-column quarter (and gather byte-quarter)
  const int l = tid & 63;
  const int l15 = l & 15;
  const int lq = l >> 4;
  const int e0 = blockIdx.x * 64;

  // per-lane invariant LDS offsets (all linear, no swizzle)
  const int aoff = lq * 1024 + l15 * 16;  // B-frag read: + kt*4096 + nt*256

  // ---- gather: wave wn holds feature-quarter [64wn,+64) of its lane's edge row ----
  // write chunk (8wn + c), byte l*16: 64 lanes contiguous 1 KB -> conflict-free
  {
    int e = e0 + l;
    if (e >= E) e = E - 1;
    const int idx = eidx[(wn >> 1) * E + e];  // wn<2: drug, wn>=2: dis
    const unsigned short* src = ((wn < 2) ? drugB : disB) + (long)idx * 128 + (wn & 1) * 64;
    unsigned char* wbase = Abase + wn * 8192 + l * 16;
#pragma unroll
    for (int c = 0; c < 8; ++c) {
      const u16x8 v = *(const u16x8*)(src + c * 8);
      *(u16x8*)(wbase + c * 1024) = v;
    }
  }

  // ---- W2 A-frags resident (hidden under gather), bias/W3 float4 per lane ----
  u16x8 w2f[4];
#pragma unroll
  for (int kt = 0; kt < 4; ++kt)
    w2f[kt] = *(const u16x8*)(w2frag + ((wn * 4 + kt) * 64 + l) * 8);
  const float4 b1v0 = *(const float4*)(b1 + 32 * wn + 4 * lq);
  const float4 b1v1 = *(const float4*)(b1 + 32 * wn + 16 + 4 * lq);
  const float4 b2v = *(const float4*)(b2 + 16 * wn + 4 * lq);
  const float4 w3v = *(const float4*)(W3 + 16 * wn + 4 * lq);
  __syncthreads();

  // ---- layer 1: D1[unit][edge]; A = W1 frags (2-deep stream), B = edge frags from LDS ----
  f32x4 acc1[2][4];
#pragma unroll
  for (int uti = 0; uti < 2; ++uti)
#pragma unroll
    for (int nt = 0; nt < 4; ++nt) acc1[uti][nt] = (f32x4){0.f, 0.f, 0.f, 0.f};

  const unsigned short* w1p = w1frag + ((2 * wn) * 512 + l) * 8;
  u16x8 nf[2][2];  // [kt parity][uti]; kt+2 prefetch
  nf[0][0] = *(const u16x8*)(w1p);
  nf[0][1] = *(const u16x8*)(w1p + 512 * 8);
  nf[1][0] = *(const u16x8*)(w1p + 64 * 8);
  nf[1][1] = *(const u16x8*)(w1p + (512 + 64) * 8);
#pragma unroll
  for (int kt = 0; kt < 8; ++kt) {
    const u16x8 c0 = nf[kt & 1][0], c1 = nf[kt & 1][1];
    if (kt < 6) {
      nf[kt & 1][0] = *(const u16x8*)(w1p + ((kt + 2) * 64) * 8);
      nf[kt & 1][1] = *(const u16x8*)(w1p + ((512 + (kt + 2) * 64)) * 8);
    }
#pragma unroll
    for (int nt = 0; nt < 4; ++nt) {
      const u16x8 b = *(const u16x8*)(Abase + kt * 4096 + nt * 256 + aoff);
      acc1[0][nt] = mfma_bf16(c0, b, acc1[0][nt]);
      acc1[1][nt] = mfma_bf16(c1, b, acc1[1][nt]);
    }
  }
  __syncthreads();  // all waves done reading A before H1 overwrites chunks 0..15

  // ---- H1 epilogue: bias+relu, pack 4 bf16 -> 8B write, chunked layout ----
  // lane holds D1[u0..u0+4)[e], u0 = 32wn+16uti+4lq, e = 16nt+l15.
  // H1 chunk = (u0>>5)*4 + ((u0&31)>>3) = wn*4 + 2uti + (lq>>1); byte-in-slot (u0&7)*2.
  {
    unsigned char* hw = Abase + wn * 4096 + (lq >> 1) * 1024 + (lq & 1) * 8 + l15 * 16;
#pragma unroll
    for (int uti = 0; uti < 2; ++uti) {
      const float4 bv = uti ? b1v1 : b1v0;
#pragma unroll
      for (int nt = 0; nt < 4; ++nt) {
        float h0 = acc1[uti][nt][0] + bv.x; h0 = h0 > 0.f ? h0 : 0.f;
        float h1 = acc1[uti][nt][1] + bv.y; h1 = h1 > 0.f ? h1 : 0.f;
        float h2 = acc1[uti][nt][2] + bv.z; h2 = h2 > 0.f ? h2 : 0.f;
        float h3 = acc1[uti][nt][3] + bv.w; h3 = h3 > 0.f ? h3 : 0.f;
        ushort4 hv;
        hv.x = f2b(h0); hv.y = f2b(h1); hv.z = f2b(h2); hv.w = f2b(h3);
        *(ushort4*)(hw + uti * 2048 + nt * 256) = hv;
      }
    }
  }
  __syncthreads();

  // ---- layer 2: D2[n2][edge]; A = W2 frags (resident), B = H1 frags from LDS ----
  f32x4 acc2[4];
#pragma unroll
  for (int nt = 0; nt < 4; ++nt) acc2[nt] = (f32x4){0.f, 0.f, 0.f, 0.f};
#pragma unroll
  for (int kt = 0; kt < 4; ++kt) {
#pragma unroll
    for (int nt = 0; nt < 4; ++nt) {
      const u16x8 b = *(const u16x8*)(Abase + kt * 4096 + nt * 256 + aoff);
      acc2[nt] = mfma_bf16(w2f[kt], b, acc2[nt]);
    }
  }

  // ---- layer 3: relu(.+b2) dot W3 (4 units per lane), reduce over lq with 2 shuffles ----
#pragma unroll
  for (int nt = 0; nt < 4; ++nt) {
    float h0 = acc2[nt][0] + b2v.x; h0 = h0 > 0.f ? h0 : 0.f;
    float h1 = acc2[nt][1] + b2v.y; h1 = h1 > 0.f ? h1 : 0.f;
    float h2 = acc2[nt][2] + b2v.z; h2 = h2 > 0.f ? h2 : 0.f;
    float h3 = acc2[nt][3] + b2v.w; h3 = h3 > 0.f ? h3 : 0.f;
    float s = h0 * w3v.x + h1 * w3v.y + h2 * w3v.z + h3 * w3v.w;
    s += __shfl_xor(s, 16, 64);
    s += __shfl_xor(s, 32, 64);
    if (l < 16) partials[wn * 64 + 16 * nt + l15] = s;
  }
  __syncthreads();

  if (tid < 64) {
    const int e = e0 + tid;
    if (e < E) {
      out[e] = partials[tid] + partials[64 + tid] + partials[128 + tid] +
               partials[192 + tid] + b3[0];
    }
  }
}

extern "C" void kernel_launch(void* const* d_in, const int* in_sizes, int n_in,
                              void* d_out, int out_size, void* d_ws, size_t ws_size,
                              hipStream_t stream) {
  const float* drug = (const float*)d_in[0];
  const float* dis = (const float*)d_in[1];
  const int* eidx = (const int*)d_in[2];
  const float* W1 = (const float*)d_in[3];
  const float* b1 = (const float*)d_in[4];
  const float* W2 = (const float*)d_in[5];
  const float* b2 = (const float*)d_in[6];
  const float* W3 = (const float*)d_in[7];
  const float* b3 = (const float*)d_in[8];
  float* out = (float*)d_out;

  const int na = in_sizes[0];           // 10000*128
  const int nb = in_sizes[1];           // 5000*128
  const int E = in_sizes[2] / 2;        // 2e6

  unsigned short* ws = (unsigned short*)d_ws;
  unsigned short* drugB = ws;
  unsigned short* disB = ws + na;
  unsigned short* w1f = ws + na + nb;
  unsigned short* w2f = w1f + 128 * 256;
  // total ws use: (na+nb)*2 + 81920 bytes ~= 3.92 MB

  const int tct = (na + nb) >> 3;
  cvt_tables<<<(tct + 255) / 256, 256, 0, stream>>>(drug, dis, drugB, disB, na, nb);
  cvt_weights<<<20, 256, 0, stream>>>(W1, W2, w1f, w2f);

  const int grid = (E + 63) / 64;
  mlp_fused<<<grid, 256, 0, stream>>>(drugB, disB, eidx, w1f, w2f, b1, b2, W3, b3, out, E);
}